// Round 10
// baseline (228.466 us; speedup 1.0000x reference)
//
#include <hip/hip_runtime.h>
#include <math.h>

typedef __attribute__((ext_vector_type(8))) _Float16 f16x8;
typedef __attribute__((ext_vector_type(4))) _Float16 f16x4;
typedef __attribute__((ext_vector_type(4))) float f32x4;

#define MFMAH(a, b, c) __builtin_amdgcn_mfma_f32_16x16x32_f16((a), (b), (c), 0, 0, 0)

// q pre-scale: 0.125 * log2(e)  (folds softmax exp->exp2 conversion into qk scale)
#define QSCALE 0.18033688011112042f
// softmax fixed offset in exp2 domain: 3 * log2(e)
#define SOFF 4.328085122666891f

// EMPIRICAL LOOP-SHAPE MATRIX (r7/r8/r9 A/Bs, do not flip-flop):
//   attn:  single-barrier dbuf ~55us; two-barrier 58.5us  (dbuf slightly better)
//   gemms: two-barrier reg-prefetch ~59us; dbuf 87.5us    (dbuf much worse)
// LDS layout (r10): fragment-major [rg][quad][l16][8] -> all staging writes and
// fragment reads are wave-contiguous 1KB = conflict-free by construction.

// ---------------- fused prep: cast x (float4), LDS-tiled weight transposes, rope ----------------
__global__ void prep_kernel(const float* __restrict__ x, const float* __restrict__ w_qkv,
                            const float* __restrict__ w_proj, _Float16* __restrict__ xb,
                            _Float16* __restrict__ wq, _Float16* __restrict__ wp,
                            float* __restrict__ ct, float* __restrict__ st,
                            float* __restrict__ xt) {
    __shared__ float tile[32][33];
    const int b = blockIdx.x, tid = threadIdx.x;
    if (b < 4096) {
        int i = (b * 256 + tid) * 4;
        float4 v = *(const float4*)&x[i];
        f16x4 h = {(_Float16)v.x, (_Float16)v.y, (_Float16)v.z, (_Float16)v.w};
        *(f16x4*)&xb[i] = h;
    } else if (b < 4096 + 3072 + 1024) {
        // weight transpose via 32x32 LDS tile: w [1024][C] -> wT [C][1024]
        int t, C;
        const float* src;
        _Float16* dst;
        if (b < 4096 + 3072) { t = b - 4096; C = 3072; src = w_qkv; dst = wq; }
        else                 { t = b - 4096 - 3072; C = 1024; src = w_proj; dst = wp; }
        const int tr = t & 31, tc = t >> 5;  // 32 row-tiles; C/32 col-tiles
        const int tx = tid & 31, ty = tid >> 5;  // ty in [0,8)
#pragma unroll
        for (int yy = 0; yy < 4; ++yy) {
            int r = ty + yy * 8;
            tile[r][tx] = src[(size_t)(tr * 32 + r) * C + tc * 32 + tx];
        }
        __syncthreads();
#pragma unroll
        for (int yy = 0; yy < 4; ++yy) {
            int r = ty + yy * 8;
            dst[(size_t)(tc * 32 + r) * 1024 + tr * 32 + tx] = (_Float16)tile[tx][r];
        }
    } else {
        int i = (b - 8192) * 256 + tid;  // 512 blocks -> 2048*64 table entries
        int n = i >> 6, d = i & 63;
        int gi = n >> 6, gj = n & 63;
        int axis = d >> 5;
        int p = (d & 31) >> 1;
        float t = axis ? (float)gj : (float)gi;
        float half = axis ? 32.0f : 16.0f;
        float inv_freq = powf(10000.0f, -(float)p * (1.0f / 16.0f));
        float fr = t * inv_freq;
        float sbase = (2.0f * p + 12.8f) / 44.8f;
        float xs = powf(sbase, (t - half) * (1.0f / 64.0f));
        ct[i] = cosf(fr);
        st[i] = sinf(fr);
        xt[i] = xs;
    }
}

// ---------------- fp16 GEMM (128x128, BK=32, two-barrier reg-prefetch, fragment-major LDS) ----------
__global__ __launch_bounds__(256) void gemm_qkv_kernel(
    const _Float16* __restrict__ A_g, const _Float16* __restrict__ B_g,
    const float* __restrict__ bias, const float* __restrict__ ctab,
    const float* __restrict__ stab, const float* __restrict__ xtab,
    _Float16* __restrict__ qb, _Float16* __restrict__ kb, _Float16* __restrict__ vt) {
    __shared__ __align__(16) _Float16 Asm[4096];  // [rg 8][quad 4][l16 16][8]
    __shared__ __align__(16) _Float16 Bsm[4096];

    const int tid = threadIdx.x;
    const int lane = tid & 63, wave = tid >> 6;
    const int quad = lane >> 4, l16 = lane & 15;
    const int wm = wave >> 1, wn = wave & 1;
    const int m0 = blockIdx.x * 128, n0 = blockIdx.y * 128;

    f32x4 zero = {0.f, 0.f, 0.f, 0.f};
    f32x4 acc[4][4];
#pragma unroll
    for (int i = 0; i < 4; ++i)
#pragma unroll
        for (int j = 0; j < 4; ++j) acc[i][j] = zero;

    // staging chunk decode: chunk c -> row = (c>>6)*16 + (c&15), koff = ((c>>4)&3)*8
    const int c1 = tid + 256;
    const int row0 = ((tid >> 6) << 4) | (tid & 15), ko0 = ((tid >> 4) & 3) << 3;
    const int row1 = ((c1 >> 6) << 4) | (c1 & 15), ko1 = ((c1 >> 4) & 3) << 3;
    const _Float16* Ap0 = &A_g[(size_t)(m0 + row0) * 1024 + ko0];
    const _Float16* Ap1 = &A_g[(size_t)(m0 + row1) * 1024 + ko1];
    const _Float16* Bp0 = &B_g[(size_t)(n0 + row0) * 1024 + ko0];
    const _Float16* Bp1 = &B_g[(size_t)(n0 + row1) * 1024 + ko1];

    f16x8 pa0 = *(const f16x8*)Ap0;
    f16x8 pa1 = *(const f16x8*)Ap1;
    f16x8 pb0 = *(const f16x8*)Bp0;
    f16x8 pb1 = *(const f16x8*)Bp1;

    for (int k0 = 0; k0 < 1024; k0 += 32) {
        __syncthreads();  // prior iteration's LDS reads complete
        *(f16x8*)&Asm[tid * 8] = pa0;   // wave-contiguous 1KB writes: conflict-free
        *(f16x8*)&Asm[c1 * 8] = pa1;
        *(f16x8*)&Bsm[tid * 8] = pb0;
        *(f16x8*)&Bsm[c1 * 8] = pb1;
        __syncthreads();

        if (k0 + 32 < 1024) {  // prefetch next tile while computing on this one
            const int kn = k0 + 32;
            pa0 = *(const f16x8*)(Ap0 + kn);
            pa1 = *(const f16x8*)(Ap1 + kn);
            pb0 = *(const f16x8*)(Bp0 + kn);
            pb1 = *(const f16x8*)(Bp1 + kn);
        }

        f16x8 af[4], bf[4];
#pragma unroll
        for (int i = 0; i < 4; ++i) {  // wave-contiguous 1KB reads: conflict-free
            af[i] = *(const f16x8*)&Asm[(wm * 4 + i) * 512 + quad * 128 + l16 * 8];
            bf[i] = *(const f16x8*)&Bsm[(wn * 4 + i) * 512 + quad * 128 + l16 * 8];
        }
#pragma unroll
        for (int i = 0; i < 4; ++i)
#pragma unroll
            for (int j = 0; j < 4; ++j) acc[i][j] = MFMAH(af[i], bf[j], acc[i][j]);
    }

    float bj[4];
#pragma unroll
    for (int j = 0; j < 4; ++j) bj[j] = bias[n0 + wn * 64 + j * 16 + l16];

    if (n0 < 2048) {
        // q/k blocks: bias + xpos rope; q additionally scaled by 0.125*log2e
#pragma unroll
        for (int i = 0; i < 4; ++i) {
#pragma unroll
            for (int r = 0; r < 4; ++r) {
                const int row = m0 + wm * 64 + i * 16 + quad * 4 + r;
                const int b = row >> 11, nrow = row & 2047;
#pragma unroll
                for (int j = 0; j < 4; ++j) {
                    const int col = n0 + wn * 64 + j * 16 + l16;
                    float v = acc[i][j][r] + bj[j];
                    float partner = __shfl_xor(v, 1);  // rotate_half pair lives in lane^1
                    const int hh = (col >> 6) & 15;
                    const int d = col & 63;
                    const size_t o = ((size_t)(b * 16 + hh) * 2048 + nrow) * 64 + d;
                    float rh = (d & 1) ? partner : -partner;
                    const int ti = nrow * 64 + d;
                    float rv = v * ctab[ti] + rh * stab[ti];
                    float xs = xtab[ti];
                    if (col < 1024)
                        qb[o] = (_Float16)(rv * xs * QSCALE);
                    else
                        kb[o] = (_Float16)(rv / xs);
                }
            }
        }
    } else {
        // v blocks: bias only; write directly transposed vt[bh][d][n] as packed 8B rows
#pragma unroll
        for (int i = 0; i < 4; ++i) {
            const int row = m0 + wm * 64 + i * 16 + quad * 4;
            const int b = row >> 11, nrow = row & 2047;
#pragma unroll
            for (int j = 0; j < 4; ++j) {
                const int col = n0 + wn * 64 + j * 16 + l16;
                const int hh = (col >> 6) & 15;
                const int d = col & 63;
                f16x4 pv4;
#pragma unroll
                for (int r = 0; r < 4; ++r) pv4[r] = (_Float16)(acc[i][j][r] + bj[j]);
                *(f16x4*)&vt[((size_t)(b * 16 + hh) * 64 + d) * 2048 + nrow] = pv4;
            }
        }
    }
}

// ---------------- proj GEMM: 128x64 tile, two-barrier reg-prefetch, fragment-major LDS ------------
__global__ __launch_bounds__(256) void gemm_proj_kernel(
    const _Float16* __restrict__ A_g, const _Float16* __restrict__ B_g,
    const float* __restrict__ bias, float* __restrict__ out) {
    __shared__ __align__(16) _Float16 Asm[4096];  // [rg 8][quad 4][l16 16][8]
    __shared__ __align__(16) _Float16 Bsm[2048];  // [rg 4][quad 4][l16 16][8]

    const int tid = threadIdx.x;
    const int lane = tid & 63, wave = tid >> 6;
    const int quad = lane >> 4, l16 = lane & 15;
    const int wm = wave >> 1, wn = wave & 1;
    const int m0 = blockIdx.x * 128, n0 = blockIdx.y * 64;

    f32x4 zero = {0.f, 0.f, 0.f, 0.f};
    f32x4 acc[4][2];
#pragma unroll
    for (int i = 0; i < 4; ++i)
#pragma unroll
        for (int j = 0; j < 2; ++j) acc[i][j] = zero;

    const int c1 = tid + 256;
    const int row0 = ((tid >> 6) << 4) | (tid & 15), ko0 = ((tid >> 4) & 3) << 3;
    const int row1 = ((c1 >> 6) << 4) | (c1 & 15), ko1 = ((c1 >> 4) & 3) << 3;
    const _Float16* Ap0 = &A_g[(size_t)(m0 + row0) * 1024 + ko0];
    const _Float16* Ap1 = &A_g[(size_t)(m0 + row1) * 1024 + ko1];
    const _Float16* Bp0 = &B_g[(size_t)(n0 + row0) * 1024 + ko0];  // rows 0..63 used

    f16x8 pa0 = *(const f16x8*)Ap0;
    f16x8 pa1 = *(const f16x8*)Ap1;
    f16x8 pb0 = *(const f16x8*)Bp0;

    for (int k0 = 0; k0 < 1024; k0 += 32) {
        __syncthreads();
        *(f16x8*)&Asm[tid * 8] = pa0;
        *(f16x8*)&Asm[c1 * 8] = pa1;
        *(f16x8*)&Bsm[tid * 8] = pb0;  // 256 chunks = 64 rows x 4 quads
        __syncthreads();

        if (k0 + 32 < 1024) {
            const int kn = k0 + 32;
            pa0 = *(const f16x8*)(Ap0 + kn);
            pa1 = *(const f16x8*)(Ap1 + kn);
            pb0 = *(const f16x8*)(Bp0 + kn);
        }

        f16x8 af[4], bf[2];
#pragma unroll
        for (int i = 0; i < 4; ++i)
            af[i] = *(const f16x8*)&Asm[(wm * 4 + i) * 512 + quad * 128 + l16 * 8];
#pragma unroll
        for (int j = 0; j < 2; ++j)
            bf[j] = *(const f16x8*)&Bsm[(wn * 2 + j) * 512 + quad * 128 + l16 * 8];
#pragma unroll
        for (int i = 0; i < 4; ++i)
#pragma unroll
            for (int j = 0; j < 2; ++j) acc[i][j] = MFMAH(af[i], bf[j], acc[i][j]);
    }

    float bj[2];
#pragma unroll
    for (int j = 0; j < 2; ++j) bj[j] = bias[n0 + wn * 32 + j * 16 + l16];
#pragma unroll
    for (int i = 0; i < 4; ++i)
#pragma unroll
        for (int r = 0; r < 4; ++r) {
            const int row = m0 + wm * 64 + i * 16 + quad * 4 + r;
#pragma unroll
            for (int j = 0; j < 2; ++j) {
                const int col = n0 + wn * 32 + j * 16 + l16;
                out[(size_t)row * 1024 + col] = acc[i][j][r] + bj[j];
            }
        }
}

// ---------------- flash attention: single-barrier K/V dbuf + XCD-aware swizzle (r9 shape) ---------
#define KLD 72   // K/V LDS row stride (fp16): 144B rows
#define PLD 72   // P LDS row stride

__global__ __launch_bounds__(256) void attn_kernel(
    const _Float16* __restrict__ qb, const _Float16* __restrict__ kb,
    const _Float16* __restrict__ vt, _Float16* __restrict__ ao) {
    __shared__ __align__(16) _Float16 Ksm0[64 * KLD], Ksm1[64 * KLD];
    __shared__ __align__(16) _Float16 Vsm0[64 * KLD], Vsm1[64 * KLD];
    __shared__ __align__(16) _Float16 Psm[4 * 32 * PLD];

    const int tid = threadIdx.x;
    const int lane = tid & 63, wave = tid >> 6;
    const int quad = lane >> 4, l16 = lane & 15;
    const int bh = blockIdx.x & 31, qt = blockIdx.x >> 5;  // XCD swizzle
    const size_t base = (size_t)bh * 2048 * 64;
    const int qrow0 = qt * 128 + wave * 32;

    f16x8 qf[2][2];
#pragma unroll
    for (int rg = 0; rg < 2; ++rg) {
        qf[rg][0] = *(const f16x8*)&qb[base + (size_t)(qrow0 + rg * 16 + l16) * 64 + quad * 8];
        qf[rg][1] = *(const f16x8*)&qb[base + (size_t)(qrow0 + rg * 16 + l16) * 64 + 32 + quad * 8];
    }

    f32x4 moff = {-SOFF, -SOFF, -SOFF, -SOFF};
    f32x4 zero = {0.f, 0.f, 0.f, 0.f};
    f32x4 o[2][4];
    float lsum[2] = {0.f, 0.f};
#pragma unroll
    for (int rg = 0; rg < 2; ++rg)
#pragma unroll
        for (int dc = 0; dc < 4; ++dc) o[rg][dc] = zero;

    const int kr0 = tid >> 3, ko0 = (tid & 7) << 3;
    const int kr1 = kr0 + 32;
    f16x8 pk0, pk1, pv0, pv1;
    auto gload = [&](int kt) {
        pk0 = *(const f16x8*)&kb[base + (size_t)(kt + kr0) * 64 + ko0];
        pk1 = *(const f16x8*)&kb[base + (size_t)(kt + kr1) * 64 + ko0];
        pv0 = *(const f16x8*)&vt[((size_t)bh * 64 + kr0) * 2048 + kt + ko0];
        pv1 = *(const f16x8*)&vt[((size_t)bh * 64 + kr1) * 2048 + kt + ko0];
    };
    auto stage = [&](_Float16* Ks, _Float16* Vs) {
        *(f16x8*)&Ks[kr0 * KLD + ko0] = pk0;
        *(f16x8*)&Ks[kr1 * KLD + ko0] = pk1;
        *(f16x8*)&Vs[kr0 * KLD + ko0] = pv0;
        *(f16x8*)&Vs[kr1 * KLD + ko0] = pv1;
    };

    _Float16* Pw = &Psm[wave * 32 * PLD];

    auto compute = [&](const _Float16* Ks, const _Float16* Vs) {
        f32x4 s[2][4];
#pragma unroll
        for (int kg = 0; kg < 4; ++kg) {
            f16x8 kf0 = *(const f16x8*)&Ks[(kg * 16 + l16) * KLD + quad * 8];
            f16x8 kf1 = *(const f16x8*)&Ks[(kg * 16 + l16) * KLD + 32 + quad * 8];
            s[0][kg] = MFMAH(kf0, qf[0][0], moff);
            s[0][kg] = MFMAH(kf1, qf[0][1], s[0][kg]);
            s[1][kg] = MFMAH(kf0, qf[1][0], moff);
            s[1][kg] = MFMAH(kf1, qf[1][1], s[1][kg]);
        }
#pragma unroll
        for (int rg = 0; rg < 2; ++rg)
#pragma unroll
            for (int kg = 0; kg < 4; ++kg) {
                float p0 = __builtin_amdgcn_exp2f(s[rg][kg][0]);
                float p1 = __builtin_amdgcn_exp2f(s[rg][kg][1]);
                float p2 = __builtin_amdgcn_exp2f(s[rg][kg][2]);
                float p3 = __builtin_amdgcn_exp2f(s[rg][kg][3]);
                lsum[rg] += (p0 + p1) + (p2 + p3);
                f16x4 ph = {(_Float16)p0, (_Float16)p1, (_Float16)p2, (_Float16)p3};
                *(f16x4*)&Pw[(rg * 16 + l16) * PLD + kg * 16 + quad * 4] = ph;
            }
        f16x8 pf[2][2];
#pragma unroll
        for (int rg = 0; rg < 2; ++rg) {
            pf[rg][0] = *(const f16x8*)&Pw[(rg * 16 + l16) * PLD + quad * 8];
            pf[rg][1] = *(const f16x8*)&Pw[(rg * 16 + l16) * PLD + 32 + quad * 8];
        }
#pragma unroll
        for (int dc = 0; dc < 4; ++dc) {
            f16x8 vf0 = *(const f16x8*)&Vs[(dc * 16 + l16) * KLD + quad * 8];
            f16x8 vf1 = *(const f16x8*)&Vs[(dc * 16 + l16) * KLD + 32 + quad * 8];
#pragma unroll
            for (int rg = 0; rg < 2; ++rg) {
                o[rg][dc] = MFMAH(pf[rg][0], vf0, o[rg][dc]);
                o[rg][dc] = MFMAH(pf[rg][1], vf1, o[rg][dc]);
            }
        }
    };

    gload(0);
    stage(Ksm0, Vsm0);
    gload(64);
    __syncthreads();

    for (int it = 0; it < 32; it += 2) {
        stage(Ksm1, Vsm1);                       // tile it+1
        if (it + 2 < 32) gload((it + 2) * 64);
        compute(Ksm0, Vsm0);                     // tile it
        __syncthreads();
        if (it + 2 < 32) stage(Ksm0, Vsm0);      // tile it+2
        if (it + 3 < 32) gload((it + 3) * 64);
        compute(Ksm1, Vsm1);                     // tile it+1
        __syncthreads();
    }

    float linv[2][4];
#pragma unroll
    for (int rg = 0; rg < 2; ++rg) {
        float v = lsum[rg];
        v += __shfl_xor(v, 16);
        v += __shfl_xor(v, 32);
        v = 1.0f / v;
#pragma unroll
        for (int r = 0; r < 4; ++r) linv[rg][r] = __shfl(v, quad * 4 + r);
    }

    const int b = bh >> 4, hh = bh & 15;
#pragma unroll
    for (int rg = 0; rg < 2; ++rg)
#pragma unroll
        for (int dc = 0; dc < 4; ++dc)
#pragma unroll
            for (int r = 0; r < 4; ++r) {
                float v = o[rg][dc][r] * linv[rg][r];
                const int qrow = qrow0 + rg * 16 + quad * 4 + r;
                const size_t oi = ((size_t)(b * 2048 + qrow)) * 1024 + hh * 64 + dc * 16 + l16;
                ao[oi] = (_Float16)v;
            }
}

// ---------------- launcher ----------------
extern "C" void kernel_launch(void* const* d_in, const int* in_sizes, int n_in,
                              void* d_out, int out_size, void* d_ws, size_t ws_size,
                              hipStream_t stream) {
    const float* x = (const float*)d_in[0];
    const float* w_qkv = (const float*)d_in[1];
    const float* b_qkv = (const float*)d_in[2];
    const float* w_proj = (const float*)d_in[3];
    const float* b_proj = (const float*)d_in[4];
    float* out = (float*)d_out;

    char* ws = (char*)d_ws;
    size_t off = 0;
    auto take = [&](size_t bytes) { char* p = ws + off; off += bytes; return p; };
    _Float16* xbuf   = (_Float16*)take(8388608);   // x fp16 [4096][1024]
    _Float16* wqkvT  = (_Float16*)take(6291456);   // w_qkv^T [3072][1024]
    _Float16* wprojT = (_Float16*)take(2097152);   // w_proj^T [1024][1024]
    _Float16* qbuf   = (_Float16*)take(8388608);   // q (rope, *0.125*log2e)
    _Float16* kbuf   = (_Float16*)take(8388608);
    _Float16* vtbuf  = (_Float16*)take(8388608);   // v^T [bh][d][n], written by gemm_qkv
    float* ctab      = (float*)take(524288);
    float* stab      = (float*)take(524288);
    float* xtab      = (float*)take(524288);
    _Float16* ao = xbuf;  // x dead after gemm_qkv; attn output reuses it

    prep_kernel<<<8704, 256, 0, stream>>>(x, w_qkv, w_proj, xbuf, wqkvT, wprojT,
                                          ctab, stab, xtab);
    gemm_qkv_kernel<<<dim3(32, 24), 256, 0, stream>>>(xbuf, wqkvT, b_qkv,
                                                      ctab, stab, xtab, qbuf, kbuf, vtbuf);
    attn_kernel<<<512, 256, 0, stream>>>(qbuf, kbuf, vtbuf, ao);
    gemm_proj_kernel<<<dim3(32, 16), 256, 0, stream>>>(ao, wprojT, b_proj, out);
}

// Round 11
// 199.987 us; speedup vs baseline: 1.1424x; 1.1424x over previous
//
#include <hip/hip_runtime.h>
#include <math.h>

typedef __attribute__((ext_vector_type(8))) _Float16 f16x8;
typedef __attribute__((ext_vector_type(4))) _Float16 f16x4;
typedef __attribute__((ext_vector_type(4))) float f32x4;

#define MFMAH(a, b, c) __builtin_amdgcn_mfma_f32_16x16x32_f16((a), (b), (c), 0, 0, 0)

// q pre-scale: 0.125 * log2(e)  (folds softmax exp->exp2 conversion into qk scale)
#define QSCALE 0.18033688011112042f
// softmax fixed offset in exp2 domain: 3 * log2(e)
#define SOFF 4.328085122666891f

// EMPIRICAL MATRIX (r7-r10 A/Bs, do not flip-flop):
//   attn:  single-barrier dbuf ~55us beats two-barrier 58.5us
//   gemms: two-barrier reg-prefetch beats dbuf (59 vs 87.5)
//   gemm global mapping MUST keep 4-lanes-per-64B-segment (r10's transposed
//   mapping cost +21us from 4x TA requests despite zero LDS conflicts)
// r11 LDS: row-major [128][32] with k-chunk XOR swizzle slot = quad ^ ((row>>1)&3)
//   -> staging writes and fragment reads both 2-way-max (free), zero padding.

// ---------------- fused prep: cast x (float4), LDS-tiled weight transposes, rope ----------------
__global__ void prep_kernel(const float* __restrict__ x, const float* __restrict__ w_qkv,
                            const float* __restrict__ w_proj, _Float16* __restrict__ xb,
                            _Float16* __restrict__ wq, _Float16* __restrict__ wp,
                            float* __restrict__ ct, float* __restrict__ st,
                            float* __restrict__ xt) {
    __shared__ float tile[32][33];
    const int b = blockIdx.x, tid = threadIdx.x;
    if (b < 4096) {
        int i = (b * 256 + tid) * 4;
        float4 v = *(const float4*)&x[i];
        f16x4 h = {(_Float16)v.x, (_Float16)v.y, (_Float16)v.z, (_Float16)v.w};
        *(f16x4*)&xb[i] = h;
    } else if (b < 4096 + 3072 + 1024) {
        // weight transpose via 32x32 LDS tile: w [1024][C] -> wT [C][1024]
        int t, C;
        const float* src;
        _Float16* dst;
        if (b < 4096 + 3072) { t = b - 4096; C = 3072; src = w_qkv; dst = wq; }
        else                 { t = b - 4096 - 3072; C = 1024; src = w_proj; dst = wp; }
        const int tr = t & 31, tc = t >> 5;
        const int tx = tid & 31, ty = tid >> 5;
#pragma unroll
        for (int yy = 0; yy < 4; ++yy) {
            int r = ty + yy * 8;
            tile[r][tx] = src[(size_t)(tr * 32 + r) * C + tc * 32 + tx];
        }
        __syncthreads();
#pragma unroll
        for (int yy = 0; yy < 4; ++yy) {
            int r = ty + yy * 8;
            dst[(size_t)(tc * 32 + r) * 1024 + tr * 32 + tx] = (_Float16)tile[tx][r];
        }
    } else {
        int i = (b - 8192) * 256 + tid;
        int n = i >> 6, d = i & 63;
        int gi = n >> 6, gj = n & 63;
        int axis = d >> 5;
        int p = (d & 31) >> 1;
        float t = axis ? (float)gj : (float)gi;
        float half = axis ? 32.0f : 16.0f;
        float inv_freq = powf(10000.0f, -(float)p * (1.0f / 16.0f));
        float fr = t * inv_freq;
        float sbase = (2.0f * p + 12.8f) / 44.8f;
        float xs = powf(sbase, (t - half) * (1.0f / 64.0f));
        ct[i] = cosf(fr);
        st[i] = sinf(fr);
        xt[i] = xs;
    }
}

// ---------------- fp16 GEMM (128x128, BK=32, two-barrier reg-prefetch, XOR-swizzled LDS) ----------
__global__ __launch_bounds__(256) void gemm_qkv_kernel(
    const _Float16* __restrict__ A_g, const _Float16* __restrict__ B_g,
    const float* __restrict__ bias, const float* __restrict__ ctab,
    const float* __restrict__ stab, const float* __restrict__ xtab,
    _Float16* __restrict__ qb, _Float16* __restrict__ kb, _Float16* __restrict__ vt) {
    __shared__ __align__(16) _Float16 Asm[4096];  // [row 128][slot 4][8], slot = q ^ ((row>>1)&3)
    __shared__ __align__(16) _Float16 Bsm[4096];

    const int tid = threadIdx.x;
    const int lane = tid & 63, wave = tid >> 6;
    const int quad = lane >> 4, l16 = lane & 15;
    const int wm = wave >> 1, wn = wave & 1;
    const int m0 = blockIdx.x * 128, n0 = blockIdx.y * 128;

    f32x4 zero = {0.f, 0.f, 0.f, 0.f};
    f32x4 acc[4][4];
#pragma unroll
    for (int i = 0; i < 4; ++i)
#pragma unroll
        for (int j = 0; j < 4; ++j) acc[i][j] = zero;

    // r9 global mapping: chunk c -> row=c>>2, quad=c&3 (4 lanes per 64B segment)
    const int c1 = tid + 256;
    const int row0 = tid >> 2, q0 = tid & 3;
    const int row1 = c1 >> 2, q1 = c1 & 3;
    // swizzled LDS element index
    const int w0 = row0 * 32 + ((q0 ^ ((row0 >> 1) & 3)) << 3);
    const int w1 = row1 * 32 + ((q1 ^ ((row1 >> 1) & 3)) << 3);
    const _Float16* Ap0 = &A_g[(size_t)(m0 + row0) * 1024 + (q0 << 3)];
    const _Float16* Ap1 = &A_g[(size_t)(m0 + row1) * 1024 + (q1 << 3)];
    const _Float16* Bp0 = &B_g[(size_t)(n0 + row0) * 1024 + (q0 << 3)];
    const _Float16* Bp1 = &B_g[(size_t)(n0 + row1) * 1024 + (q1 << 3)];

    f16x8 pa0 = *(const f16x8*)Ap0;
    f16x8 pa1 = *(const f16x8*)Ap1;
    f16x8 pb0 = *(const f16x8*)Bp0;
    f16x8 pb1 = *(const f16x8*)Bp1;

    const int sw = (l16 >> 1) & 3;  // read-side swizzle (i-independent)

    for (int k0 = 0; k0 < 1024; k0 += 32) {
        __syncthreads();  // prior iteration's LDS reads complete
        *(f16x8*)&Asm[w0] = pa0;
        *(f16x8*)&Asm[w1] = pa1;
        *(f16x8*)&Bsm[w0] = pb0;
        *(f16x8*)&Bsm[w1] = pb1;
        __syncthreads();

        if (k0 + 32 < 1024) {  // prefetch next tile while computing on this one
            const int kn = k0 + 32;
            pa0 = *(const f16x8*)(Ap0 + kn);
            pa1 = *(const f16x8*)(Ap1 + kn);
            pb0 = *(const f16x8*)(Bp0 + kn);
            pb1 = *(const f16x8*)(Bp1 + kn);
        }

        f16x8 af[4], bf[4];
#pragma unroll
        for (int i = 0; i < 4; ++i) {
            af[i] = *(const f16x8*)&Asm[(wm * 64 + i * 16 + l16) * 32 + ((quad ^ sw) << 3)];
            bf[i] = *(const f16x8*)&Bsm[(wn * 64 + i * 16 + l16) * 32 + ((quad ^ sw) << 3)];
        }
#pragma unroll
        for (int i = 0; i < 4; ++i)
#pragma unroll
            for (int j = 0; j < 4; ++j) acc[i][j] = MFMAH(af[i], bf[j], acc[i][j]);
    }

    float bj[4];
#pragma unroll
    for (int j = 0; j < 4; ++j) bj[j] = bias[n0 + wn * 64 + j * 16 + l16];

    if (n0 < 2048) {
        // q/k blocks: bias + xpos rope; q additionally scaled by 0.125*log2e
#pragma unroll
        for (int i = 0; i < 4; ++i) {
#pragma unroll
            for (int r = 0; r < 4; ++r) {
                const int row = m0 + wm * 64 + i * 16 + quad * 4 + r;
                const int b = row >> 11, nrow = row & 2047;
#pragma unroll
                for (int j = 0; j < 4; ++j) {
                    const int col = n0 + wn * 64 + j * 16 + l16;
                    float v = acc[i][j][r] + bj[j];
                    float partner = __shfl_xor(v, 1);  // rotate_half pair lives in lane^1
                    const int hh = (col >> 6) & 15;
                    const int d = col & 63;
                    const size_t o = ((size_t)(b * 16 + hh) * 2048 + nrow) * 64 + d;
                    float rh = (d & 1) ? partner : -partner;
                    const int ti = nrow * 64 + d;
                    float rv = v * ctab[ti] + rh * stab[ti];
                    float xs = xtab[ti];
                    if (col < 1024)
                        qb[o] = (_Float16)(rv * xs * QSCALE);
                    else
                        kb[o] = (_Float16)(rv / xs);
                }
            }
        }
    } else {
        // v blocks: bias only; write directly transposed vt[bh][d][n] as packed 8B rows
#pragma unroll
        for (int i = 0; i < 4; ++i) {
            const int row = m0 + wm * 64 + i * 16 + quad * 4;
            const int b = row >> 11, nrow = row & 2047;
#pragma unroll
            for (int j = 0; j < 4; ++j) {
                const int col = n0 + wn * 64 + j * 16 + l16;
                const int hh = (col >> 6) & 15;
                const int d = col & 63;
                f16x4 pv4;
#pragma unroll
                for (int r = 0; r < 4; ++r) pv4[r] = (_Float16)(acc[i][j][r] + bj[j]);
                *(f16x4*)&vt[((size_t)(b * 16 + hh) * 64 + d) * 2048 + nrow] = pv4;
            }
        }
    }
}

// ---------------- proj GEMM: 128x64 tile, two-barrier reg-prefetch, XOR-swizzled LDS --------------
__global__ __launch_bounds__(256) void gemm_proj_kernel(
    const _Float16* __restrict__ A_g, const _Float16* __restrict__ B_g,
    const float* __restrict__ bias, float* __restrict__ out) {
    __shared__ __align__(16) _Float16 Asm[4096];  // [row 128][slot 4][8]
    __shared__ __align__(16) _Float16 Bsm[2048];  // [row 64][slot 4][8]

    const int tid = threadIdx.x;
    const int lane = tid & 63, wave = tid >> 6;
    const int quad = lane >> 4, l16 = lane & 15;
    const int wm = wave >> 1, wn = wave & 1;
    const int m0 = blockIdx.x * 128, n0 = blockIdx.y * 64;

    f32x4 zero = {0.f, 0.f, 0.f, 0.f};
    f32x4 acc[4][2];
#pragma unroll
    for (int i = 0; i < 4; ++i)
#pragma unroll
        for (int j = 0; j < 2; ++j) acc[i][j] = zero;

    const int c1 = tid + 256;
    const int row0 = tid >> 2, q0 = tid & 3;   // rows 0..63
    const int row1 = c1 >> 2, q1 = c1 & 3;     // rows 64..127
    const int w0 = row0 * 32 + ((q0 ^ ((row0 >> 1) & 3)) << 3);
    const int w1 = row1 * 32 + ((q1 ^ ((row1 >> 1) & 3)) << 3);
    const _Float16* Ap0 = &A_g[(size_t)(m0 + row0) * 1024 + (q0 << 3)];
    const _Float16* Ap1 = &A_g[(size_t)(m0 + row1) * 1024 + (q1 << 3)];
    const _Float16* Bp0 = &B_g[(size_t)(n0 + row0) * 1024 + (q0 << 3)];  // rows 0..63 used

    f16x8 pa0 = *(const f16x8*)Ap0;
    f16x8 pa1 = *(const f16x8*)Ap1;
    f16x8 pb0 = *(const f16x8*)Bp0;

    const int sw = (l16 >> 1) & 3;

    for (int k0 = 0; k0 < 1024; k0 += 32) {
        __syncthreads();
        *(f16x8*)&Asm[w0] = pa0;
        *(f16x8*)&Asm[w1] = pa1;
        *(f16x8*)&Bsm[w0] = pb0;
        __syncthreads();

        if (k0 + 32 < 1024) {
            const int kn = k0 + 32;
            pa0 = *(const f16x8*)(Ap0 + kn);
            pa1 = *(const f16x8*)(Ap1 + kn);
            pb0 = *(const f16x8*)(Bp0 + kn);
        }

        f16x8 af[4], bf[2];
#pragma unroll
        for (int i = 0; i < 4; ++i)
            af[i] = *(const f16x8*)&Asm[(wm * 64 + i * 16 + l16) * 32 + ((quad ^ sw) << 3)];
#pragma unroll
        for (int j = 0; j < 2; ++j)
            bf[j] = *(const f16x8*)&Bsm[(wn * 32 + j * 16 + l16) * 32 + ((quad ^ sw) << 3)];
#pragma unroll
        for (int i = 0; i < 4; ++i)
#pragma unroll
            for (int j = 0; j < 2; ++j) acc[i][j] = MFMAH(af[i], bf[j], acc[i][j]);
    }

    float bj[2];
#pragma unroll
    for (int j = 0; j < 2; ++j) bj[j] = bias[n0 + wn * 32 + j * 16 + l16];
#pragma unroll
    for (int i = 0; i < 4; ++i)
#pragma unroll
        for (int r = 0; r < 4; ++r) {
            const int row = m0 + wm * 64 + i * 16 + quad * 4 + r;
#pragma unroll
            for (int j = 0; j < 2; ++j) {
                const int col = n0 + wn * 32 + j * 16 + l16;
                out[(size_t)row * 1024 + col] = acc[i][j][r] + bj[j];
            }
        }
}

// ---------------- flash attention: single-barrier K/V dbuf + XCD-aware swizzle (r9 shape) ---------
#define KLD 72   // K/V LDS row stride (fp16): 144B rows
#define PLD 72   // P LDS row stride

__global__ __launch_bounds__(256) void attn_kernel(
    const _Float16* __restrict__ qb, const _Float16* __restrict__ kb,
    const _Float16* __restrict__ vt, _Float16* __restrict__ ao) {
    __shared__ __align__(16) _Float16 Ksm0[64 * KLD], Ksm1[64 * KLD];
    __shared__ __align__(16) _Float16 Vsm0[64 * KLD], Vsm1[64 * KLD];
    __shared__ __align__(16) _Float16 Psm[4 * 32 * PLD];

    const int tid = threadIdx.x;
    const int lane = tid & 63, wave = tid >> 6;
    const int quad = lane >> 4, l16 = lane & 15;
    const int bh = blockIdx.x & 31, qt = blockIdx.x >> 5;  // XCD swizzle
    const size_t base = (size_t)bh * 2048 * 64;
    const int qrow0 = qt * 128 + wave * 32;

    f16x8 qf[2][2];
#pragma unroll
    for (int rg = 0; rg < 2; ++rg) {
        qf[rg][0] = *(const f16x8*)&qb[base + (size_t)(qrow0 + rg * 16 + l16) * 64 + quad * 8];
        qf[rg][1] = *(const f16x8*)&qb[base + (size_t)(qrow0 + rg * 16 + l16) * 64 + 32 + quad * 8];
    }

    f32x4 moff = {-SOFF, -SOFF, -SOFF, -SOFF};
    f32x4 zero = {0.f, 0.f, 0.f, 0.f};
    f32x4 o[2][4];
    float lsum[2] = {0.f, 0.f};
#pragma unroll
    for (int rg = 0; rg < 2; ++rg)
#pragma unroll
        for (int dc = 0; dc < 4; ++dc) o[rg][dc] = zero;

    const int kr0 = tid >> 3, ko0 = (tid & 7) << 3;
    const int kr1 = kr0 + 32;
    f16x8 pk0, pk1, pv0, pv1;
    auto gload = [&](int kt) {
        pk0 = *(const f16x8*)&kb[base + (size_t)(kt + kr0) * 64 + ko0];
        pk1 = *(const f16x8*)&kb[base + (size_t)(kt + kr1) * 64 + ko0];
        pv0 = *(const f16x8*)&vt[((size_t)bh * 64 + kr0) * 2048 + kt + ko0];
        pv1 = *(const f16x8*)&vt[((size_t)bh * 64 + kr1) * 2048 + kt + ko0];
    };
    auto stage = [&](_Float16* Ks, _Float16* Vs) {
        *(f16x8*)&Ks[kr0 * KLD + ko0] = pk0;
        *(f16x8*)&Ks[kr1 * KLD + ko0] = pk1;
        *(f16x8*)&Vs[kr0 * KLD + ko0] = pv0;
        *(f16x8*)&Vs[kr1 * KLD + ko0] = pv1;
    };

    _Float16* Pw = &Psm[wave * 32 * PLD];

    auto compute = [&](const _Float16* Ks, const _Float16* Vs) {
        f32x4 s[2][4];
#pragma unroll
        for (int kg = 0; kg < 4; ++kg) {
            f16x8 kf0 = *(const f16x8*)&Ks[(kg * 16 + l16) * KLD + quad * 8];
            f16x8 kf1 = *(const f16x8*)&Ks[(kg * 16 + l16) * KLD + 32 + quad * 8];
            s[0][kg] = MFMAH(kf0, qf[0][0], moff);
            s[0][kg] = MFMAH(kf1, qf[0][1], s[0][kg]);
            s[1][kg] = MFMAH(kf0, qf[1][0], moff);
            s[1][kg] = MFMAH(kf1, qf[1][1], s[1][kg]);
        }
#pragma unroll
        for (int rg = 0; rg < 2; ++rg)
#pragma unroll
            for (int kg = 0; kg < 4; ++kg) {
                float p0 = __builtin_amdgcn_exp2f(s[rg][kg][0]);
                float p1 = __builtin_amdgcn_exp2f(s[rg][kg][1]);
                float p2 = __builtin_amdgcn_exp2f(s[rg][kg][2]);
                float p3 = __builtin_amdgcn_exp2f(s[rg][kg][3]);
                lsum[rg] += (p0 + p1) + (p2 + p3);
                f16x4 ph = {(_Float16)p0, (_Float16)p1, (_Float16)p2, (_Float16)p3};
                *(f16x4*)&Pw[(rg * 16 + l16) * PLD + kg * 16 + quad * 4] = ph;
            }
        f16x8 pf[2][2];
#pragma unroll
        for (int rg = 0; rg < 2; ++rg) {
            pf[rg][0] = *(const f16x8*)&Pw[(rg * 16 + l16) * PLD + quad * 8];
            pf[rg][1] = *(const f16x8*)&Pw[(rg * 16 + l16) * PLD + 32 + quad * 8];
        }
#pragma unroll
        for (int dc = 0; dc < 4; ++dc) {
            f16x8 vf0 = *(const f16x8*)&Vs[(dc * 16 + l16) * KLD + quad * 8];
            f16x8 vf1 = *(const f16x8*)&Vs[(dc * 16 + l16) * KLD + 32 + quad * 8];
#pragma unroll
            for (int rg = 0; rg < 2; ++rg) {
                o[rg][dc] = MFMAH(pf[rg][0], vf0, o[rg][dc]);
                o[rg][dc] = MFMAH(pf[rg][1], vf1, o[rg][dc]);
            }
        }
    };

    gload(0);
    stage(Ksm0, Vsm0);
    gload(64);
    __syncthreads();

    for (int it = 0; it < 32; it += 2) {
        stage(Ksm1, Vsm1);                       // tile it+1
        if (it + 2 < 32) gload((it + 2) * 64);
        compute(Ksm0, Vsm0);                     // tile it
        __syncthreads();
        if (it + 2 < 32) stage(Ksm0, Vsm0);      // tile it+2
        if (it + 3 < 32) gload((it + 3) * 64);
        compute(Ksm1, Vsm1);                     // tile it+1
        __syncthreads();
    }

    float linv[2][4];
#pragma unroll
    for (int rg = 0; rg < 2; ++rg) {
        float v = lsum[rg];
        v += __shfl_xor(v, 16);
        v += __shfl_xor(v, 32);
        v = 1.0f / v;
#pragma unroll
        for (int r = 0; r < 4; ++r) linv[rg][r] = __shfl(v, quad * 4 + r);
    }

    const int b = bh >> 4, hh = bh & 15;
#pragma unroll
    for (int rg = 0; rg < 2; ++rg)
#pragma unroll
        for (int dc = 0; dc < 4; ++dc)
#pragma unroll
            for (int r = 0; r < 4; ++r) {
                float v = o[rg][dc][r] * linv[rg][r];
                const int qrow = qrow0 + rg * 16 + quad * 4 + r;
                const size_t oi = ((size_t)(b * 2048 + qrow)) * 1024 + hh * 64 + dc * 16 + l16;
                ao[oi] = (_Float16)v;
            }
}

// ---------------- launcher ----------------
extern "C" void kernel_launch(void* const* d_in, const int* in_sizes, int n_in,
                              void* d_out, int out_size, void* d_ws, size_t ws_size,
                              hipStream_t stream) {
    const float* x = (const float*)d_in[0];
    const float* w_qkv = (const float*)d_in[1];
    const float* b_qkv = (const float*)d_in[2];
    const float* w_proj = (const float*)d_in[3];
    const float* b_proj = (const float*)d_in[4];
    float* out = (float*)d_out;

    char* ws = (char*)d_ws;
    size_t off = 0;
    auto take = [&](size_t bytes) { char* p = ws + off; off += bytes; return p; };
    _Float16* xbuf   = (_Float16*)take(8388608);   // x fp16 [4096][1024]
    _Float16* wqkvT  = (_Float16*)take(6291456);   // w_qkv^T [3072][1024]
    _Float16* wprojT = (_Float16*)take(2097152);   // w_proj^T [1024][1024]
    _Float16* qbuf   = (_Float16*)take(8388608);   // q (rope, *0.125*log2e)
    _Float16* kbuf   = (_Float16*)take(8388608);
    _Float16* vtbuf  = (_Float16*)take(8388608);   // v^T [bh][d][n], written by gemm_qkv
    float* ctab      = (float*)take(524288);
    float* stab      = (float*)take(524288);
    float* xtab      = (float*)take(524288);
    _Float16* ao = xbuf;  // x dead after gemm_qkv; attn output reuses it

    prep_kernel<<<8704, 256, 0, stream>>>(x, w_qkv, w_proj, xbuf, wqkvT, wprojT,
                                          ctab, stab, xtab);
    gemm_qkv_kernel<<<dim3(32, 24), 256, 0, stream>>>(xbuf, wqkvT, b_qkv,
                                                      ctab, stab, xtab, qbuf, kbuf, vtbuf);
    attn_kernel<<<512, 256, 0, stream>>>(qbuf, kbuf, vtbuf, ao);
    gemm_proj_kernel<<<dim3(32, 16), 256, 0, stream>>>(ao, wprojT, b_proj, out);
}